// Round 18
// baseline (486.229 us; speedup 1.0000x reference)
//
#include <hip/hip_runtime.h>
#include <math.h>

#define NODES 81
#define T_STEPS 12
#define NSEQ 41472
#define HID 128
#define SEQB 32               // sequences per block

typedef unsigned short ushort;
typedef unsigned int uint;
typedef __attribute__((ext_vector_type(8))) _Float16 half8;
typedef __attribute__((ext_vector_type(4))) float f32x4;

#define MFMA(A, B, C) __builtin_amdgcn_mfma_f32_16x16x32_f16((A), (B), (C), 0, 0, 0)

// fast sigmoid/tanh: v_exp_f32 (2^x) + v_rcp_f32, ~2e-7 rel err
__device__ __forceinline__ float sigf(float v) {
    return __builtin_amdgcn_rcpf(1.f + __builtin_amdgcn_exp2f(v * -1.442695041f));
}
__device__ __forceinline__ float tanhf_(float v) {
    return fmaf(2.f, __builtin_amdgcn_rcpf(1.f + __builtin_amdgcn_exp2f(v * -2.885390082f)), -1.f);
}

// ---------------------------------------------------------------------------
// Prep: MFMA-fragment-major fp16 weights, ORIGINAL gate order (verified R10-16).
// Layout per matrix: [ks(4)][nt(32)][lane(64)][j(8)] _Float16,
// value = W[n*128+k]; k = ks*32 + (lane>>4)*8 + j, n = nt*16 + (lane&15).
// Gate type t4, unit-group gr of a tile: nt = t4*8 + gr.
// Plus per-unit packed float4 params: wq/b0q/b1q[u*4+t4] (fp32, exact).
// ---------------------------------------------------------------------------
__global__ void prep_kernel(const float* __restrict__ Whh0,
                            const float* __restrict__ Wih1,
                            const float* __restrict__ Whh1,
                            const float* __restrict__ Wih0,
                            const float* __restrict__ bih0, const float* __restrict__ bhh0,
                            const float* __restrict__ bih1, const float* __restrict__ bhh1,
                            _Float16* __restrict__ WF0,
                            _Float16* __restrict__ WF1i,
                            _Float16* __restrict__ WF1h,
                            float* __restrict__ wq,
                            float* __restrict__ b0q,
                            float* __restrict__ b1q)
{
    int idx = blockIdx.x * 256 + threadIdx.x;   // 198144 total, exact
    if (idx < 196608) {
        int mat = idx >> 16;              // 65536 per matrix
        int li  = idx & 65535;
        int j   = li & 7;
        int l   = (li >> 3) & 63;
        int nt  = (li >> 9) & 31;
        int ks  = li >> 14;
        int k = ks * 32 + (l >> 4) * 8 + j;
        int n = nt * 16 + (l & 15);
        const float* W = (mat == 0) ? Whh0 : (mat == 1 ? Wih1 : Whh1);
        _Float16* D = (mat == 0) ? WF0 : (mat == 1 ? WF1i : WF1h);
        D[li] = (_Float16)W[n * 128 + k];
    } else if (idx < 197120) {
        int jp = idx - 196608;
        int u = jp >> 2, t4 = jp & 3;
        wq[jp] = Wih0[t4 * 128 + u];
    } else if (idx < 197632) {
        int jp = idx - 197120;
        int u = jp >> 2, t4 = jp & 3;
        b0q[jp] = bih0[t4 * 128 + u] + bhh0[t4 * 128 + u];
    } else if (idx < 198144) {
        int jp = idx - 197632;
        int u = jp >> 2, t4 = jp & 3;
        b1q[jp] = bih1[t4 * 128 + u] + bhh1[t4 * 128 + u];
    }
}

// ---------------------------------------------------------------------------
// income = einsum('bta,an->bnt'); stored t-major: x[t][seq], seq = b*81+n
// ---------------------------------------------------------------------------
__global__ void income_kernel(const float* __restrict__ g_data,
                              const float* __restrict__ w,
                              float* __restrict__ x)
{
    int idx = blockIdx.x * 256 + threadIdx.x;   // 497664 exactly
    int n = idx % NODES;
    int r = idx / NODES;
    int t = r % T_STEPS;
    int b = r / T_STEPS;
    const float* grow = g_data + (b * T_STEPS + t) * NODES;
    float s = 0.f;
    #pragma unroll 3
    for (int a = 0; a < NODES; ++a)
        s += grow[a] * w[a * NODES + n];
    x[t * NSEQ + b * NODES + n] = s;
}

// ---------------------------------------------------------------------------
// Fused 2-layer LSTM + FC head on fp16 MFMA. R17: SEQB=32 (halves the L2
// weight stream to 5.97 GB -> 193 us floor at R11's measured 31 TB/s) made
// register-feasible by GATE-TYPE PASS-SPLITTING: each matmul runs as two
// half-passes over t4 in {0,1} then {2,3}. Per half-pass live set: acc 16 +
// saved-gate 16 + B-in-flight <=32 (only 2 frags/ks touched, bounded by
// construction) + c 16 + misc ~25 ~= 110 < the 128-VGPR wall. A
// sched_barrier(0) between halves pins the load window (anti-R8).
// Block = 32 seqs, 512 threads = 8 waves. Wave gr owns unit-group gr:
// n-tiles {gr, gr+8, gr+16, gr+24} (= i,f,g,o) x 2 m-tiles. D = h x W^T:
// acc[mt][th][r]: seq = mt*16+l16*4+r, unit = gr*16+l15 (R13-verified).
// h double-buffered fp16 in LDS: hA[buf][kq16][m32][j8], 16 KB/layer.
// ONE barrier/step (R11/R13 race table). Spill sentinel: WRITE ~160 KB.
// ---------------------------------------------------------------------------
__global__ __launch_bounds__(512, 1) void lstm_main(
    const float* __restrict__ x,        // [12][NSEQ]
    const _Float16* __restrict__ WF0,
    const _Float16* __restrict__ WF1i,
    const _Float16* __restrict__ WF1h,
    const float* __restrict__ wq,       // [128][4] packed per-unit
    const float* __restrict__ b0q,      // [128][4]
    const float* __restrict__ b1q,      // [128][4]
    const float* __restrict__ fc1_w,    // [32][128]
    const float* __restrict__ fc1_b,    // [32]
    const float* __restrict__ fc2_w,    // [32]
    const float* __restrict__ fc2_b,    // [1]
    float* __restrict__ out)            // [NSEQ]
{
    __shared__ __align__(16) _Float16 hA0[8192];   // [2][kq16][m32][j8] 16 KB
    __shared__ __align__(16) _Float16 hA1[8192];   // 16 KB

    const int tid = threadIdx.x;
    const int l   = tid & 63;
    const int gr  = tid >> 6;          // 0..7 unit-group
    const int l15 = l & 15;
    const int l16 = l >> 4;
    const int u   = gr * 16 + l15;     // owned unit 0..127
    const int seq0 = blockIdx.x * SEQB;

    for (int i = tid; i < 4096; i += 512) {
        ((uint*)hA0)[i] = 0u; ((uint*)hA1)[i] = 0u;
    }

    // lane-invariant B fragment bases (frag = ks*16384 + t4*4096 + gr*512 + l*8)
    const _Float16* wfb0 = WF0  + gr * 512 + l * 8;
    const _Float16* wfb1 = WF1i + gr * 512 + l * 8;
    const _Float16* wfb2 = WF1h + gr * 512 + l * 8;

    const float4 wv  = *(const float4*)(wq  + u * 4);
    const float4 bv0 = *(const float4*)(b0q + u * 4);
    const float4 bv1 = *(const float4*)(b1q + u * 4);

    float c0[8], c1[8];                 // [mt*4+r]
    #pragma unroll
    for (int i = 0; i < 8; ++i) { c0[i] = 0.f; c1[i] = 0.f; }
    __syncthreads();

    const int wrbase = (u >> 3) * 256 + (u & 7);   // h-write base within a buffer

    int cur = 0;
    for (int t = 0; t < T_STEPS; ++t) {
        const int nxt = cur ^ 1;
        const float4 xv0 = *(const float4*)(x + t * NSEQ + seq0 + l16 * 4);
        const float4 xv1 = *(const float4*)(x + t * NSEQ + seq0 + 16 + l16 * 4);

        f32x4 acc[2][2];                // [mt][t4-within-half]
        f32x4 sg[2][2];                 // saved gates of half 0 (t4 = 0,1 = i,f)

        // ======== layer 0, half A (t4 = 0,1) : i,f gates ========
        #pragma unroll
        for (int mt = 0; mt < 2; ++mt)
            #pragma unroll
            for (int th = 0; th < 2; ++th) acc[mt][th] = (f32x4){0.f, 0.f, 0.f, 0.f};
        #pragma unroll
        for (int ks = 0; ks < 4; ++ks) {
            const int ao = cur * 4096 + (ks * 4 + l16) * 256 + l15 * 8;
            half8 a0 = *(const half8*)(hA0 + ao);
            half8 a1 = *(const half8*)(hA0 + ao + 128);
            half8 b0 = *(const half8*)(wfb0 + ks * 16384 + 0 * 4096);
            half8 b1 = *(const half8*)(wfb0 + ks * 16384 + 1 * 4096);
            acc[0][0] = MFMA(a0, b0, acc[0][0]);
            acc[1][0] = MFMA(a1, b0, acc[1][0]);
            acc[0][1] = MFMA(a0, b1, acc[0][1]);
            acc[1][1] = MFMA(a1, b1, acc[1][1]);
        }
        sg[0][0] = acc[0][0]; sg[0][1] = acc[0][1];
        sg[1][0] = acc[1][0]; sg[1][1] = acc[1][1];
        __builtin_amdgcn_sched_barrier(0);
        // ======== layer 0, half B (t4 = 2,3) : g,o gates ========
        #pragma unroll
        for (int mt = 0; mt < 2; ++mt)
            #pragma unroll
            for (int th = 0; th < 2; ++th) acc[mt][th] = (f32x4){0.f, 0.f, 0.f, 0.f};
        #pragma unroll
        for (int ks = 0; ks < 4; ++ks) {
            const int ao = cur * 4096 + (ks * 4 + l16) * 256 + l15 * 8;
            half8 a0 = *(const half8*)(hA0 + ao);
            half8 a1 = *(const half8*)(hA0 + ao + 128);
            half8 b2 = *(const half8*)(wfb0 + ks * 16384 + 2 * 4096);
            half8 b3 = *(const half8*)(wfb0 + ks * 16384 + 3 * 4096);
            acc[0][0] = MFMA(a0, b2, acc[0][0]);
            acc[1][0] = MFMA(a1, b2, acc[1][0]);
            acc[0][1] = MFMA(a0, b3, acc[0][1]);
            acc[1][1] = MFMA(a1, b3, acc[1][1]);
        }
        // ======== layer 0 update ========
        #pragma unroll
        for (int mt = 0; mt < 2; ++mt) {
            #pragma unroll
            for (int r = 0; r < 4; ++r) {
                int m = mt * 16 + l16 * 4 + r;
                float xvr = mt ? xv1[r] : xv0[r];
                float gi = sg[mt][0][r]  + xvr * wv.x + bv0.x;
                float gf = sg[mt][1][r]  + xvr * wv.y + bv0.y;
                float gg = acc[mt][0][r] + xvr * wv.z + bv0.z;
                float go = acc[mt][1][r] + xvr * wv.w + bv0.w;
                float iv = sigf(gi), fv = sigf(gf), gv = tanhf_(gg), ov = sigf(go);
                float c = fv * c0[mt * 4 + r] + iv * gv;
                c0[mt * 4 + r] = c;
                hA0[nxt * 4096 + wrbase + m * 8] = (_Float16)(ov * tanhf_(c));
            }
        }
        __syncthreads();   // the ONE barrier: new h0 visible; prior reads done

        // ======== layer 1, half A (t4 = 0,1): h0_new@W1i + h1_old@W1h ========
        #pragma unroll
        for (int mt = 0; mt < 2; ++mt)
            #pragma unroll
            for (int th = 0; th < 2; ++th) acc[mt][th] = (f32x4){0.f, 0.f, 0.f, 0.f};
        #pragma unroll
        for (int ks = 0; ks < 4; ++ks) {
            const int ao = nxt * 4096 + (ks * 4 + l16) * 256 + l15 * 8;   // new h0
            half8 a0 = *(const half8*)(hA0 + ao);
            half8 a1 = *(const half8*)(hA0 + ao + 128);
            half8 b0 = *(const half8*)(wfb1 + ks * 16384 + 0 * 4096);
            half8 b1 = *(const half8*)(wfb1 + ks * 16384 + 1 * 4096);
            acc[0][0] = MFMA(a0, b0, acc[0][0]);
            acc[1][0] = MFMA(a1, b0, acc[1][0]);
            acc[0][1] = MFMA(a0, b1, acc[0][1]);
            acc[1][1] = MFMA(a1, b1, acc[1][1]);
        }
        #pragma unroll
        for (int ks = 0; ks < 4; ++ks) {
            const int ao = cur * 4096 + (ks * 4 + l16) * 256 + l15 * 8;   // old h1
            half8 a0 = *(const half8*)(hA1 + ao);
            half8 a1 = *(const half8*)(hA1 + ao + 128);
            half8 b0 = *(const half8*)(wfb2 + ks * 16384 + 0 * 4096);
            half8 b1 = *(const half8*)(wfb2 + ks * 16384 + 1 * 4096);
            acc[0][0] = MFMA(a0, b0, acc[0][0]);
            acc[1][0] = MFMA(a1, b0, acc[1][0]);
            acc[0][1] = MFMA(a0, b1, acc[0][1]);
            acc[1][1] = MFMA(a1, b1, acc[1][1]);
        }
        sg[0][0] = acc[0][0]; sg[0][1] = acc[0][1];
        sg[1][0] = acc[1][0]; sg[1][1] = acc[1][1];
        __builtin_amdgcn_sched_barrier(0);
        // ======== layer 1, half B (t4 = 2,3) ========
        #pragma unroll
        for (int mt = 0; mt < 2; ++mt)
            #pragma unroll
            for (int th = 0; th < 2; ++th) acc[mt][th] = (f32x4){0.f, 0.f, 0.f, 0.f};
        #pragma unroll
        for (int ks = 0; ks < 4; ++ks) {
            const int ao = nxt * 4096 + (ks * 4 + l16) * 256 + l15 * 8;
            half8 a0 = *(const half8*)(hA0 + ao);
            half8 a1 = *(const half8*)(hA0 + ao + 128);
            half8 b2 = *(const half8*)(wfb1 + ks * 16384 + 2 * 4096);
            half8 b3 = *(const half8*)(wfb1 + ks * 16384 + 3 * 4096);
            acc[0][0] = MFMA(a0, b2, acc[0][0]);
            acc[1][0] = MFMA(a1, b2, acc[1][0]);
            acc[0][1] = MFMA(a0, b3, acc[0][1]);
            acc[1][1] = MFMA(a1, b3, acc[1][1]);
        }
        #pragma unroll
        for (int ks = 0; ks < 4; ++ks) {
            const int ao = cur * 4096 + (ks * 4 + l16) * 256 + l15 * 8;
            half8 a0 = *(const half8*)(hA1 + ao);
            half8 a1 = *(const half8*)(hA1 + ao + 128);
            half8 b2 = *(const half8*)(wfb2 + ks * 16384 + 2 * 4096);
            half8 b3 = *(const half8*)(wfb2 + ks * 16384 + 3 * 4096);
            acc[0][0] = MFMA(a0, b2, acc[0][0]);
            acc[1][0] = MFMA(a1, b2, acc[1][0]);
            acc[0][1] = MFMA(a0, b3, acc[0][1]);
            acc[1][1] = MFMA(a1, b3, acc[1][1]);
        }
        // ======== layer 1 update ========
        #pragma unroll
        for (int mt = 0; mt < 2; ++mt) {
            #pragma unroll
            for (int r = 0; r < 4; ++r) {
                int m = mt * 16 + l16 * 4 + r;
                float gi = sg[mt][0][r]  + bv1.x;
                float gf = sg[mt][1][r]  + bv1.y;
                float gg = acc[mt][0][r] + bv1.z;
                float go = acc[mt][1][r] + bv1.w;
                float iv = sigf(gi), fv = sigf(gf), gv = tanhf_(gg), ov = sigf(go);
                float c = fv * c1[mt * 4 + r] + iv * gv;
                c1[mt * 4 + r] = c;
                hA1[nxt * 4096 + wrbase + m * 8] = (_Float16)(ov * tanhf_(c));
            }
        }
        // no second barrier: next step's post-L0 barrier separates all pairs
        cur = nxt;
    }
    __syncthreads();                    // final h1 visible to all waves

    // ===== FC head: 1024 tasks = 32 seq x 32 j over 512 threads =====
    float* hidb = (float*)hA0;          // overlay: hid [32][33]
    float hv[2];
    #pragma unroll
    for (int r2 = 0; r2 < 2; ++r2) {
        int task = tid + r2 * 512;
        int s = task >> 5, j = task & 31;
        float sum = fc1_b[j];
        const float* wrow = fc1_w + j * HID;
        #pragma unroll 4
        for (int kq = 0; kq < 16; ++kq) {
            half8 H = *(const half8*)(hA1 + cur * 4096 + kq * 256 + s * 8);
            #pragma unroll
            for (int j8 = 0; j8 < 8; ++j8)
                sum += (float)H[j8] * wrow[kq * 8 + j8];
        }
        hv[r2] = fmaxf(sum, 0.f);
    }
    __syncthreads();                    // hA0 region free for overlay
    #pragma unroll
    for (int r2 = 0; r2 < 2; ++r2) {
        int task = tid + r2 * 512;
        hidb[(task >> 5) * 33 + (task & 31)] = hv[r2];
    }
    __syncthreads();
    if (tid < SEQB) {
        float sum = fc2_b[0];
        #pragma unroll
        for (int j = 0; j < 32; ++j) sum += hidb[tid * 33 + j] * fc2_w[j];
        out[seq0 + tid] = fmaxf(sum, 0.f);
    }
}

// ---------------------------------------------------------------------------
extern "C" void kernel_launch(void* const* d_in, const int* in_sizes, int n_in,
                              void* d_out, int out_size, void* d_ws, size_t ws_size,
                              hipStream_t stream)
{
    const float* g_data = (const float*)d_in[0];
    const float* weights = (const float*)d_in[1];
    const float* Wih0   = (const float*)d_in[2];
    const float* Whh0   = (const float*)d_in[3];
    const float* bih0   = (const float*)d_in[4];
    const float* bhh0   = (const float*)d_in[5];
    const float* Wih1   = (const float*)d_in[6];
    const float* Whh1   = (const float*)d_in[7];
    const float* bih1   = (const float*)d_in[8];
    const float* bhh1   = (const float*)d_in[9];
    const float* fc1_w  = (const float*)d_in[10];
    const float* fc1_b  = (const float*)d_in[11];
    const float* fc2_w  = (const float*)d_in[12];
    const float* fc2_b  = (const float*)d_in[13];
    float* out = (float*)d_out;

    float* ws = (float*)d_ws;
    float*     x    = ws;                              // 497664 f
    _Float16*  WF0  = (_Float16*)(x + NSEQ * T_STEPS); // 65536 h
    _Float16*  WF1i = WF0 + 65536;                     // 65536 h
    _Float16*  WF1h = WF1i + 65536;                    // 65536 h
    float*     wqp  = (float*)(WF1h + 65536);          // 512 f
    float*     b0q  = wqp + 512;                       // 512 f
    float*     b1q  = b0q + 512;                       // 512 f

    prep_kernel<<<774, 256, 0, stream>>>(Whh0, Wih1, Whh1, Wih0, bih0, bhh0, bih1, bhh1,
                                         WF0, WF1i, WF1h, wqp, b0q, b1q);
    income_kernel<<<1944, 256, 0, stream>>>(g_data, weights, x);
    lstm_main<<<NSEQ / SEQB, 512, 0, stream>>>(x, WF0, WF1i, WF1h, wqp, b0q, b1q,
                                               fc1_w, fc1_b, fc2_w, fc2_b, out);
}

// Round 19
// 383.935 us; speedup vs baseline: 1.2664x; 1.2664x over previous
//
#include <hip/hip_runtime.h>
#include <math.h>

#define NODES 81
#define T_STEPS 12
#define NSEQ 41472
#define HID 128
#define SEQB 16               // sequences per block

typedef unsigned short ushort;
typedef unsigned int uint;
typedef __attribute__((ext_vector_type(8))) _Float16 half8;
typedef __attribute__((ext_vector_type(4))) float f32x4;

#define MFMA(A, B, C) __builtin_amdgcn_mfma_f32_16x16x32_f16((A), (B), (C), 0, 0, 0)

// fast sigmoid/tanh: v_exp_f32 (2^x) + v_rcp_f32, ~2e-7 rel err
__device__ __forceinline__ float sigf(float v) {
    return __builtin_amdgcn_rcpf(1.f + __builtin_amdgcn_exp2f(v * -1.442695041f));
}
__device__ __forceinline__ float tanhf_(float v) {
    return fmaf(2.f, __builtin_amdgcn_rcpf(1.f + __builtin_amdgcn_exp2f(v * -2.885390082f)), -1.f);
}

// ---------------------------------------------------------------------------
// Prep: MFMA-fragment-major fp16 weights, ORIGINAL gate order (verified R10+).
// Layout per matrix: [ks(4)][nt(32)][lane(64)][j(8)] _Float16,
// value = W[n*128+k]; k = ks*32 + (lane>>4)*8 + j, n = nt*16 + (lane&15).
// Gate type t4, unit-group gr of a tile: nt = t4*8 + gr.
// Plus per-unit packed float4 params: wq/b0q/b1q[u*4+t4] (fp32, exact).
// ---------------------------------------------------------------------------
__global__ void prep_kernel(const float* __restrict__ Whh0,
                            const float* __restrict__ Wih1,
                            const float* __restrict__ Whh1,
                            const float* __restrict__ Wih0,
                            const float* __restrict__ bih0, const float* __restrict__ bhh0,
                            const float* __restrict__ bih1, const float* __restrict__ bhh1,
                            _Float16* __restrict__ WF0,
                            _Float16* __restrict__ WF1i,
                            _Float16* __restrict__ WF1h,
                            float* __restrict__ wq,
                            float* __restrict__ b0q,
                            float* __restrict__ b1q)
{
    int idx = blockIdx.x * 256 + threadIdx.x;   // 198144 total, exact
    if (idx < 196608) {
        int mat = idx >> 16;              // 65536 per matrix
        int li  = idx & 65535;
        int j   = li & 7;
        int l   = (li >> 3) & 63;
        int nt  = (li >> 9) & 31;
        int ks  = li >> 14;
        int k = ks * 32 + (l >> 4) * 8 + j;
        int n = nt * 16 + (l & 15);
        const float* W = (mat == 0) ? Whh0 : (mat == 1 ? Wih1 : Whh1);
        _Float16* D = (mat == 0) ? WF0 : (mat == 1 ? WF1i : WF1h);
        D[li] = (_Float16)W[n * 128 + k];
    } else if (idx < 197120) {
        int jp = idx - 196608;
        int u = jp >> 2, t4 = jp & 3;
        wq[jp] = Wih0[t4 * 128 + u];
    } else if (idx < 197632) {
        int jp = idx - 197120;
        int u = jp >> 2, t4 = jp & 3;
        b0q[jp] = bih0[t4 * 128 + u] + bhh0[t4 * 128 + u];
    } else if (idx < 198144) {
        int jp = idx - 197632;
        int u = jp >> 2, t4 = jp & 3;
        b1q[jp] = bih1[t4 * 128 + u] + bhh1[t4 * 128 + u];
    }
}

// ---------------------------------------------------------------------------
// income = einsum('bta,an->bnt'); stored t-major: x[t][seq], seq = b*81+n
// ---------------------------------------------------------------------------
__global__ void income_kernel(const float* __restrict__ g_data,
                              const float* __restrict__ w,
                              float* __restrict__ x)
{
    int idx = blockIdx.x * 256 + threadIdx.x;   // 497664 exactly
    int n = idx % NODES;
    int r = idx / NODES;
    int t = r % T_STEPS;
    int b = r / T_STEPS;
    const float* grow = g_data + (b * T_STEPS + t) * NODES;
    float s = 0.f;
    #pragma unroll 3
    for (int a = 0; a < NODES; ++a)
        s += grow[a] * w[a * NODES + n];
    x[t * NSEQ + b * NODES + n] = s;
}

// ---------------------------------------------------------------------------
// Fused 2-layer LSTM + FC head on fp16 MFMA — R11 configuration (best: 383us,
// 90% of the 34.5 TB/s L2 weight-stream roofline; 7 structural variants
// R12-R17 all regressed on the 128-VGPR allocator wall).
// Block = 16 seqs, 512 threads = 8 waves. Wave gr owns unit-group gr:
// n-tiles {gr, gr+8, gr+16, gr+24} (= i,f,g,o) x 1 m-tile; acc = 16 VGPR.
// 48 B-fragments as declared arrays -> compiler remats the invariant loads
// per phase with batched issue (memory-level parallelism, 31 TB/s stream).
// h-state double-buffered fp16 in LDS: hA[buf][kq16][m16][j8], 16 KB total.
// ONE barrier per step (race table verified). ks loops fully unrolled.
// ---------------------------------------------------------------------------
__global__ __launch_bounds__(512, 1) void lstm_main(
    const float* __restrict__ x,        // [12][NSEQ]
    const _Float16* __restrict__ WF0,
    const _Float16* __restrict__ WF1i,
    const _Float16* __restrict__ WF1h,
    const float* __restrict__ wq,       // [128][4] packed per-unit
    const float* __restrict__ b0q,      // [128][4]
    const float* __restrict__ b1q,      // [128][4]
    const float* __restrict__ fc1_w,    // [32][128]
    const float* __restrict__ fc1_b,    // [32]
    const float* __restrict__ fc2_w,    // [32]
    const float* __restrict__ fc2_b,    // [1]
    float* __restrict__ out)            // [NSEQ]
{
    __shared__ __align__(16) _Float16 hA0[4096];   // [2][kq16][m16][j8]
    __shared__ __align__(16) _Float16 hA1[4096];

    const int tid = threadIdx.x;
    const int l   = tid & 63;
    const int gr  = tid >> 6;          // 0..7 unit-group
    const int l15 = l & 15;
    const int l16 = l >> 4;
    const int u   = gr * 16 + l15;     // owned unit 0..127
    const int seq0 = blockIdx.x * SEQB;

    for (int i = tid; i < 2048; i += 512) {
        ((uint*)hA0)[i] = 0u; ((uint*)hA1)[i] = 0u;
    }

    // ---- 48 step-invariant B fragments as declared arrays (remat pattern) ----
    const _Float16* wfb0 = WF0  + gr * 512 + l * 8;
    const _Float16* wfb1 = WF1i + gr * 512 + l * 8;
    const _Float16* wfb2 = WF1h + gr * 512 + l * 8;
    half8 B0[4][4], B1[4][4], B2[4][4];   // [ks][t4], fully static indexing
    #pragma unroll
    for (int ks = 0; ks < 4; ++ks)
        #pragma unroll
        for (int t4 = 0; t4 < 4; ++t4) {
            B0[ks][t4] = *(const half8*)(wfb0 + ks * 16384 + t4 * 4096);
            B1[ks][t4] = *(const half8*)(wfb1 + ks * 16384 + t4 * 4096);
            B2[ks][t4] = *(const half8*)(wfb2 + ks * 16384 + t4 * 4096);
        }

    const float4 wv  = *(const float4*)(wq  + u * 4);
    const float4 bv0 = *(const float4*)(b0q + u * 4);
    const float4 bv1 = *(const float4*)(b1q + u * 4);

    float c0[4], c1[4];                 // [r]
    #pragma unroll
    for (int i = 0; i < 4; ++i) { c0[i] = 0.f; c1[i] = 0.f; }
    __syncthreads();

    const int wrbase = (u >> 3) * 128 + (u & 7);   // h-write base (fp16 elems)

    int cur = 0;
    for (int t = 0; t < T_STEPS; ++t) {
        const int nxt = cur ^ 1;
        const float4 xv4 = *(const float4*)(x + t * NSEQ + seq0 + l16 * 4);

        f32x4 acc[4];                   // [gate-type]

        // ===== layer 0 matmul: h0 @ Whh0 =====
        #pragma unroll
        for (int t4 = 0; t4 < 4; ++t4) acc[t4] = (f32x4){0.f, 0.f, 0.f, 0.f};
        #pragma unroll
        for (int ks = 0; ks < 4; ++ks) {
            half8 a = *(const half8*)(hA0 + cur * 2048 + (ks * 4 + l16) * 128 + l15 * 8);
            #pragma unroll
            for (int t4 = 0; t4 < 4; ++t4) acc[t4] = MFMA(a, B0[ks][t4], acc[t4]);
        }
        // ===== layer 0 update (in-register activation) =====
        #pragma unroll
        for (int r = 0; r < 4; ++r) {
            int m = l16 * 4 + r;
            float gi = acc[0][r] + xv4[r] * wv.x + bv0.x;
            float gf = acc[1][r] + xv4[r] * wv.y + bv0.y;
            float gg = acc[2][r] + xv4[r] * wv.z + bv0.z;
            float go = acc[3][r] + xv4[r] * wv.w + bv0.w;
            float iv = sigf(gi), fv = sigf(gf), gv = tanhf_(gg), ov = sigf(go);
            float c = fv * c0[r] + iv * gv;
            c0[r] = c;
            hA0[nxt * 2048 + wrbase + m * 8] = (_Float16)(ov * tanhf_(c));
        }
        __syncthreads();   // the ONE barrier: new h0 visible; prior reads done

        // ===== layer 1 matmul: h0_new @ Wih1 + h1_old @ Whh1 =====
        #pragma unroll
        for (int t4 = 0; t4 < 4; ++t4) acc[t4] = (f32x4){0.f, 0.f, 0.f, 0.f};
        #pragma unroll
        for (int ks = 0; ks < 4; ++ks) {
            half8 a = *(const half8*)(hA0 + nxt * 2048 + (ks * 4 + l16) * 128 + l15 * 8);
            #pragma unroll
            for (int t4 = 0; t4 < 4; ++t4) acc[t4] = MFMA(a, B1[ks][t4], acc[t4]);
        }
        #pragma unroll
        for (int ks = 0; ks < 4; ++ks) {
            half8 a = *(const half8*)(hA1 + cur * 2048 + (ks * 4 + l16) * 128 + l15 * 8);
            #pragma unroll
            for (int t4 = 0; t4 < 4; ++t4) acc[t4] = MFMA(a, B2[ks][t4], acc[t4]);
        }
        // ===== layer 1 update =====
        #pragma unroll
        for (int r = 0; r < 4; ++r) {
            int m = l16 * 4 + r;
            float gi = acc[0][r] + bv1.x;
            float gf = acc[1][r] + bv1.y;
            float gg = acc[2][r] + bv1.z;
            float go = acc[3][r] + bv1.w;
            float iv = sigf(gi), fv = sigf(gf), gv = tanhf_(gg), ov = sigf(go);
            float c = fv * c1[r] + iv * gv;
            c1[r] = c;
            hA1[nxt * 2048 + wrbase + m * 8] = (_Float16)(ov * tanhf_(c));
        }
        // no second barrier: next step's post-L0 barrier separates all pairs
        cur = nxt;
    }
    __syncthreads();                    // final h1 visible to all waves

    // ===== FC head: 512 tasks = 16 seq x 32 j, one per thread =====
    float* hidb = (float*)hA0;          // overlay: hid [16][33]
    {
        int s = tid >> 5, j = tid & 31;
        float sum = fc1_b[j];
        const float* wrow = fc1_w + j * HID;
        #pragma unroll 4
        for (int kq = 0; kq < 16; ++kq) {
            half8 H = *(const half8*)(hA1 + cur * 2048 + kq * 128 + s * 8);
            #pragma unroll
            for (int j8 = 0; j8 < 8; ++j8)
                sum += (float)H[j8] * wrow[kq * 8 + j8];
        }
        float hv = fmaxf(sum, 0.f);
        __syncthreads();                // hA0 region free for overlay
        hidb[s * 33 + j] = hv;
    }
    __syncthreads();
    if (tid < SEQB) {
        float sum = fc2_b[0];
        #pragma unroll
        for (int j = 0; j < 32; ++j) sum += hidb[tid * 33 + j] * fc2_w[j];
        out[seq0 + tid] = fmaxf(sum, 0.f);
    }
}

// ---------------------------------------------------------------------------
extern "C" void kernel_launch(void* const* d_in, const int* in_sizes, int n_in,
                              void* d_out, int out_size, void* d_ws, size_t ws_size,
                              hipStream_t stream)
{
    const float* g_data = (const float*)d_in[0];
    const float* weights = (const float*)d_in[1];
    const float* Wih0   = (const float*)d_in[2];
    const float* Whh0   = (const float*)d_in[3];
    const float* bih0   = (const float*)d_in[4];
    const float* bhh0   = (const float*)d_in[5];
    const float* Wih1   = (const float*)d_in[6];
    const float* Whh1   = (const float*)d_in[7];
    const float* bih1   = (const float*)d_in[8];
    const float* bhh1   = (const float*)d_in[9];
    const float* fc1_w  = (const float*)d_in[10];
    const float* fc1_b  = (const float*)d_in[11];
    const float* fc2_w  = (const float*)d_in[12];
    const float* fc2_b  = (const float*)d_in[13];
    float* out = (float*)d_out;

    float* ws = (float*)d_ws;
    float*     x    = ws;                              // 497664 f
    _Float16*  WF0  = (_Float16*)(x + NSEQ * T_STEPS); // 65536 h
    _Float16*  WF1i = WF0 + 65536;                     // 65536 h
    _Float16*  WF1h = WF1i + 65536;                    // 65536 h
    float*     wqp  = (float*)(WF1h + 65536);          // 512 f
    float*     b0q  = wqp + 512;                       // 512 f
    float*     b1q  = b0q + 512;                       // 512 f

    prep_kernel<<<774, 256, 0, stream>>>(Whh0, Wih1, Whh1, Wih0, bih0, bhh0, bih1, bhh1,
                                         WF0, WF1i, WF1h, wqp, b0q, b1q);
    income_kernel<<<1944, 256, 0, stream>>>(g_data, weights, x);
    lstm_main<<<NSEQ / SEQB, 512, 0, stream>>>(x, WF0, WF1i, WF1h, wqp, b0q, b1q,
                                               fc1_w, fc1_b, fc2_w, fc2_b, out);
}